// Round 1
// baseline (113.752 us; speedup 1.0000x reference)
//
#include <hip/hip_runtime.h>

#define NROWS 1024
#define DIMS  512
#define KC    32
#define LDK   68   // padded leading dim (floats): 16B-aligned rows, benign bank aliasing

// ws layout (floats):
//   [0    .. 1023] sq_s        [1024 .. 2047] sq_t
//   [2048 .. 3071] rn_s        [3072 .. 4095] rn_t
//   [4096]         loss accumulator

__global__ __launch_bounds__(64) void rowstats_kernel(const float* __restrict__ S,
                                                      const float* __restrict__ T,
                                                      float* __restrict__ ws) {
    const int idx  = blockIdx.x;          // 0..2047: row (student then teacher)
    const int lane = threadIdx.x;         // 0..63
    const float* row = (idx < NROWS) ? (S + (size_t)idx * DIMS)
                                     : (T + (size_t)(idx - NROWS) * DIMS);
    const float4* p = (const float4*)row; // 128 float4 per row
    float4 v0 = p[lane];
    float4 v1 = p[lane + 64];
    float s = v0.x*v0.x + v0.y*v0.y + v0.z*v0.z + v0.w*v0.w
            + v1.x*v1.x + v1.y*v1.y + v1.z*v1.z + v1.w*v1.w;
    #pragma unroll
    for (int off = 32; off > 0; off >>= 1) s += __shfl_down(s, off);
    if (lane == 0) {
        ws[idx] = s;                              // sq
        float nrm = fmaxf(sqrtf(s), 1e-12f);      // matches F.normalize eps semantics
        ws[2048 + idx] = 1.0f / nrm;              // reciprocal norm
        if (idx == 0) ws[4096] = 0.0f;            // zero loss accumulator (ws is poisoned)
    }
}

__global__ __launch_bounds__(256) void tile_loss_kernel(const float* __restrict__ S,
                                                        const float* __restrict__ T,
                                                        float* __restrict__ ws) {
    // K-major LDS tiles: [k][row-in-tile]; row-fragment reads are contiguous -> ds_read_b128
    __shared__ float As[KC][LDK];
    __shared__ float Bs[KC][LDK];
    __shared__ float At[KC][LDK];
    __shared__ float Bt[KC][LDK];

    const int tid = threadIdx.x;
    const int ti  = blockIdx.x & 15;
    const int tj  = blockIdx.x >> 4;
    const int I   = ti * 64;
    const int J   = tj * 64;
    const int tx  = tid & 15;   // output col group
    const int ty  = tid >> 4;   // output row group
    const int c4  = (tid & 7) * 4;  // k offset (floats) within chunk for staging
    const int rr  = tid >> 3;       // 0..31: tile row for staging (also rr+32)

    float accS[4][4] = {{0.f}};
    float accT[4][4] = {{0.f}};

    const float* Sa = S + (size_t)(I + rr) * DIMS;
    const float* Sb = S + (size_t)(J + rr) * DIMS;
    const float* Ta = T + (size_t)(I + rr) * DIMS;
    const float* Tb = T + (size_t)(J + rr) * DIMS;

    for (int k0 = 0; k0 < DIMS; k0 += KC) {
        // global loads first (compiler can hoist latency above the barrier)
        float4 aS0 = *(const float4*)(Sa + k0 + c4);
        float4 aS1 = *(const float4*)(Sa + 32 * DIMS + k0 + c4);
        float4 bS0 = *(const float4*)(Sb + k0 + c4);
        float4 bS1 = *(const float4*)(Sb + 32 * DIMS + k0 + c4);
        float4 aT0 = *(const float4*)(Ta + k0 + c4);
        float4 aT1 = *(const float4*)(Ta + 32 * DIMS + k0 + c4);
        float4 bT0 = *(const float4*)(Tb + k0 + c4);
        float4 bT1 = *(const float4*)(Tb + 32 * DIMS + k0 + c4);

        __syncthreads();  // protect previous iteration's LDS reads

        As[c4+0][rr] = aS0.x; As[c4+1][rr] = aS0.y; As[c4+2][rr] = aS0.z; As[c4+3][rr] = aS0.w;
        As[c4+0][rr+32] = aS1.x; As[c4+1][rr+32] = aS1.y; As[c4+2][rr+32] = aS1.z; As[c4+3][rr+32] = aS1.w;
        Bs[c4+0][rr] = bS0.x; Bs[c4+1][rr] = bS0.y; Bs[c4+2][rr] = bS0.z; Bs[c4+3][rr] = bS0.w;
        Bs[c4+0][rr+32] = bS1.x; Bs[c4+1][rr+32] = bS1.y; Bs[c4+2][rr+32] = bS1.z; Bs[c4+3][rr+32] = bS1.w;
        At[c4+0][rr] = aT0.x; At[c4+1][rr] = aT0.y; At[c4+2][rr] = aT0.z; At[c4+3][rr] = aT0.w;
        At[c4+0][rr+32] = aT1.x; At[c4+1][rr+32] = aT1.y; At[c4+2][rr+32] = aT1.z; At[c4+3][rr+32] = aT1.w;
        Bt[c4+0][rr] = bT0.x; Bt[c4+1][rr] = bT0.y; Bt[c4+2][rr] = bT0.z; Bt[c4+3][rr] = bT0.w;
        Bt[c4+0][rr+32] = bT1.x; Bt[c4+1][rr+32] = bT1.y; Bt[c4+2][rr+32] = bT1.z; Bt[c4+3][rr+32] = bT1.w;

        __syncthreads();

        #pragma unroll 8
        for (int kk = 0; kk < KC; ++kk) {
            float4 a_s = *(const float4*)&As[kk][ty * 4];
            float4 b_s = *(const float4*)&Bs[kk][tx * 4];
            float4 a_t = *(const float4*)&At[kk][ty * 4];
            float4 b_t = *(const float4*)&Bt[kk][tx * 4];
            float av[4] = {a_s.x, a_s.y, a_s.z, a_s.w};
            float bv[4] = {b_s.x, b_s.y, b_s.z, b_s.w};
            float cv[4] = {a_t.x, a_t.y, a_t.z, a_t.w};
            float dv[4] = {b_t.x, b_t.y, b_t.z, b_t.w};
            #pragma unroll
            for (int a = 0; a < 4; ++a)
                #pragma unroll
                for (int b = 0; b < 4; ++b) {
                    accS[a][b] = fmaf(av[a], bv[b], accS[a][b]);
                    accT[a][b] = fmaf(cv[a], dv[b], accT[a][b]);
                }
        }
    }

    // epilogue: fused RKD loss contribution for this 4x4 micro-tile
    const float* sq = ws;
    const float* rn = ws + 2048;
    float sqsi[4], sqti[4], rnsi[4], rnti[4];
    float sqsj[4], sqtj[4], rnsj[4], rntj[4];
    #pragma unroll
    for (int a = 0; a < 4; ++a) {
        int i = I + ty * 4 + a;
        sqsi[a] = sq[i];        sqti[a] = sq[1024 + i];
        rnsi[a] = rn[i];        rnti[a] = rn[1024 + i];
    }
    #pragma unroll
    for (int b = 0; b < 4; ++b) {
        int j = J + tx * 4 + b;
        sqsj[b] = sq[j];        sqtj[b] = sq[1024 + j];
        rnsj[b] = rn[j];        rntj[b] = rn[1024 + j];
    }

    float local = 0.f;
    #pragma unroll
    for (int a = 0; a < 4; ++a)
        #pragma unroll
        for (int b = 0; b < 4; ++b) {
            float gs = accS[a][b], gt = accT[a][b];
            float d1 = gs * rnsi[a] * rnsj[b] - gt * rnti[a] * rntj[b];
            float d2 = (sqsi[a] + sqsj[b] - 2.f * gs) - (sqti[a] + sqtj[b] - 2.f * gt);
            local += d1 * d1 + d2 * d2;
        }

    // block reduction: wave shuffle then cross-wave via LDS
    #pragma unroll
    for (int off = 32; off > 0; off >>= 1) local += __shfl_down(local, off);
    __shared__ float wsum[4];
    if ((tid & 63) == 0) wsum[tid >> 6] = local;
    __syncthreads();
    if (tid == 0) {
        float b = wsum[0] + wsum[1] + wsum[2] + wsum[3];
        atomicAdd(&ws[4096], b);
    }
}

__global__ void finalize_kernel(const float* __restrict__ ws, float* __restrict__ out) {
    // loss = DISTANCE_W * mean(d1^2) + ANGLE_W * mean(d2^2), both means over N^2
    out[0] = ws[4096] * (1.0f / 1048576.0f);
}

extern "C" void kernel_launch(void* const* d_in, const int* in_sizes, int n_in,
                              void* d_out, int out_size, void* d_ws, size_t ws_size,
                              hipStream_t stream) {
    const float* S = (const float*)d_in[0];
    const float* T = (const float*)d_in[1];
    float* ws  = (float*)d_ws;
    float* out = (float*)d_out;

    rowstats_kernel<<<2048, 64, 0, stream>>>(S, T, ws);
    tile_loss_kernel<<<256, 256, 0, stream>>>(S, T, ws);
    finalize_kernel<<<1, 1, 0, stream>>>(ws, out);
}

// Round 2
// 84.091 us; speedup vs baseline: 1.3527x; 1.3527x over previous
//
#include <hip/hip_runtime.h>

typedef short short8 __attribute__((ext_vector_type(8)));
typedef float f32x4 __attribute__((ext_vector_type(4)));

#define DD  512
#define LDT 72   // bf16 leading dim: 144B row stride -> conflict-free b128 frag reads

// ws layout: ws[0] = float loss accumulator, ws[1] = (unsigned) block counter

__global__ void init_kernel(float* ws) {
    ws[0] = 0.0f;
    ((unsigned int*)ws)[1] = 0u;
}

__device__ __forceinline__ short to_bf16(float f) {
    unsigned int u = __float_as_uint(f);
    u += 0x7FFFu + ((u >> 16) & 1u);   // RNE (inputs are finite normals)
    return (short)(u >> 16);
}

__device__ __forceinline__ short8 pack8(float4 a, float4 b) {
    short8 r;
    r[0] = to_bf16(a.x); r[1] = to_bf16(a.y); r[2] = to_bf16(a.z); r[3] = to_bf16(a.w);
    r[4] = to_bf16(b.x); r[5] = to_bf16(b.y); r[6] = to_bf16(b.z); r[7] = to_bf16(b.w);
    return r;
}

__device__ __forceinline__ float dot4(float4 v) {
    return v.x*v.x + v.y*v.y + v.z*v.z + v.w*v.w;
}

__global__ __launch_bounds__(256, 2) void rkd_mfma_kernel(const float* __restrict__ S,
                                                          const float* __restrict__ T,
                                                          float* __restrict__ ws,
                                                          float* __restrict__ out) {
    // bf16 tiles, row-major, padded: A = 64 I-rows, B = 32 J-rows, for S and T
    __shared__ short AS[64][LDT], AT[64][LDT];
    __shared__ short BS[32][LDT], BT[32][LDT];
    __shared__ float sqAS[64], sqAT[64], sqBS[32], sqBT[32];
    __shared__ float wsum[4];

    const int t = threadIdx.x;
    const int I = (blockIdx.x >> 5) * 64;   // 16 I-tiles
    const int J = (blockIdx.x & 31) * 32;   // 32 J-tiles

    // staging role: thread t loads 8-consecutive-k chunks (chunk = (t&7), row = t>>3)
    const int r8 = t >> 3;        // 0..31
    const int co = (t & 7) * 8;   // k offset within staged 64-k slab

    const float* pA1s = S + (size_t)(I + r8) * DD + co;
    const float* pA2s = S + (size_t)(I + 32 + r8) * DD + co;
    const float* pA1t = T + (size_t)(I + r8) * DD + co;
    const float* pA2t = T + (size_t)(I + 32 + r8) * DD + co;
    const float* pBs  = S + (size_t)(J + r8) * DD + co;
    const float* pBt  = T + (size_t)(J + r8) * DD + co;

    // compute role: wave w covers G rows I+16w..+15, cols J..J+31 (2 mfma col-tiles)
    const int w    = t >> 6;
    const int L    = t & 63;
    const int m    = L & 15;
    const int quad = L >> 4;
    const int arow = w * 16 + m;
    const int koff = quad * 8;

    f32x4 aS0 = {0,0,0,0}, aS1 = {0,0,0,0};
    f32x4 aT0 = {0,0,0,0}, aT1 = {0,0,0,0};
    float p1s = 0, p2s = 0, p1t = 0, p2t = 0, pbs = 0, pbt = 0;

    for (int k0 = 0; k0 < DD; k0 += 64) {
        // 12 coalesced float4 loads (issue all before the barrier)
        float4 A1sa = *(const float4*)(pA1s + k0);
        float4 A1sb = *(const float4*)(pA1s + k0 + 4);
        float4 A2sa = *(const float4*)(pA2s + k0);
        float4 A2sb = *(const float4*)(pA2s + k0 + 4);
        float4 A1ta = *(const float4*)(pA1t + k0);
        float4 A1tb = *(const float4*)(pA1t + k0 + 4);
        float4 A2ta = *(const float4*)(pA2t + k0);
        float4 A2tb = *(const float4*)(pA2t + k0 + 4);
        float4 Bsa  = *(const float4*)(pBs + k0);
        float4 Bsb  = *(const float4*)(pBs + k0 + 4);
        float4 Bta  = *(const float4*)(pBt + k0);
        float4 Btb  = *(const float4*)(pBt + k0 + 4);

        // fp32 row-norm partials (exact data, before bf16 rounding)
        p1s += dot4(A1sa) + dot4(A1sb);
        p2s += dot4(A2sa) + dot4(A2sb);
        p1t += dot4(A1ta) + dot4(A1tb);
        p2t += dot4(A2ta) + dot4(A2tb);
        pbs += dot4(Bsa) + dot4(Bsb);
        pbt += dot4(Bta) + dot4(Btb);

        __syncthreads();  // protect previous iteration's fragment reads

        *(short8*)&AS[r8][co]      = pack8(A1sa, A1sb);
        *(short8*)&AS[32 + r8][co] = pack8(A2sa, A2sb);
        *(short8*)&AT[r8][co]      = pack8(A1ta, A1tb);
        *(short8*)&AT[32 + r8][co] = pack8(A2ta, A2tb);
        *(short8*)&BS[r8][co]      = pack8(Bsa, Bsb);
        *(short8*)&BT[r8][co]      = pack8(Bta, Btb);

        __syncthreads();

        #pragma unroll
        for (int ks = 0; ks < 2; ++ks) {
            const int kb = ks * 32 + koff;
            short8 af_s = *(const short8*)&AS[arow][kb];
            short8 af_t = *(const short8*)&AT[arow][kb];
            short8 b_s0 = *(const short8*)&BS[m][kb];
            short8 b_s1 = *(const short8*)&BS[16 + m][kb];
            short8 b_t0 = *(const short8*)&BT[m][kb];
            short8 b_t1 = *(const short8*)&BT[16 + m][kb];
            aS0 = __builtin_amdgcn_mfma_f32_16x16x32_bf16(af_s, b_s0, aS0, 0, 0, 0);
            aS1 = __builtin_amdgcn_mfma_f32_16x16x32_bf16(af_s, b_s1, aS1, 0, 0, 0);
            aT0 = __builtin_amdgcn_mfma_f32_16x16x32_bf16(af_t, b_t0, aT0, 0, 0, 0);
            aT1 = __builtin_amdgcn_mfma_f32_16x16x32_bf16(af_t, b_t1, aT1, 0, 0, 0);
        }
    }

    // finish row-norm partials: reduce over the 8 chunk-lanes (t&7), same wave
    #pragma unroll
    for (int msk = 1; msk <= 4; msk <<= 1) {
        p1s += __shfl_xor(p1s, msk);
        p2s += __shfl_xor(p2s, msk);
        p1t += __shfl_xor(p1t, msk);
        p2t += __shfl_xor(p2t, msk);
        pbs += __shfl_xor(pbs, msk);
        pbt += __shfl_xor(pbt, msk);
    }
    if ((t & 7) == 0) {
        sqAS[r8] = p1s;  sqAS[32 + r8] = p2s;
        sqAT[r8] = p1t;  sqAT[32 + r8] = p2t;
        sqBS[r8] = pbs;  sqBT[r8] = pbt;
    }
    __syncthreads();

    // epilogue: C/D layout col = lane&15, row = quad*4 + reg (verified m89/m91)
    float js0 = sqBS[m],      js1 = sqBS[16 + m];
    float jt0 = sqBT[m],      jt1 = sqBT[16 + m];
    float rjs0 = 1.0f / fmaxf(sqrtf(js0), 1e-12f);
    float rjs1 = 1.0f / fmaxf(sqrtf(js1), 1e-12f);
    float rjt0 = 1.0f / fmaxf(sqrtf(jt0), 1e-12f);
    float rjt1 = 1.0f / fmaxf(sqrtf(jt1), 1e-12f);

    float local = 0.0f;
    const int ib = w * 16 + quad * 4;
    #pragma unroll
    for (int reg = 0; reg < 4; ++reg) {
        const int r = ib + reg;
        float is = sqAS[r], it = sqAT[r];
        float ris = 1.0f / fmaxf(sqrtf(is), 1e-12f);
        float rit = 1.0f / fmaxf(sqrtf(it), 1e-12f);

        float gs0 = aS0[reg], gt0 = aT0[reg];
        float d1 = gs0 * ris * rjs0 - gt0 * rit * rjt0;
        float d2 = (is + js0 - 2.0f * gs0) - (it + jt0 - 2.0f * gt0);
        local += d1 * d1 + d2 * d2;

        float gs1 = aS1[reg], gt1 = aT1[reg];
        float e1 = gs1 * ris * rjs1 - gt1 * rit * rjt1;
        float e2 = (is + js1 - 2.0f * gs1) - (it + jt1 - 2.0f * gt1);
        local += e1 * e1 + e2 * e2;
    }

    // block reduction
    #pragma unroll
    for (int off = 32; off > 0; off >>= 1) local += __shfl_down(local, off);
    if (L == 0) wsum[w] = local;
    __syncthreads();

    if (t == 0) {
        float blk = wsum[0] + wsum[1] + wsum[2] + wsum[3];
        atomicAdd(&ws[0], blk);
        __threadfence();
        unsigned int old = atomicAdd((unsigned int*)ws + 1, 1u);
        if (old == 511u) {  // last of 512 blocks: all acc-adds are visible
            float tot = atomicAdd(&ws[0], 0.0f);
            out[0] = tot * (1.0f / 1048576.0f);
        }
    }
}

extern "C" void kernel_launch(void* const* d_in, const int* in_sizes, int n_in,
                              void* d_out, int out_size, void* d_ws, size_t ws_size,
                              hipStream_t stream) {
    const float* S = (const float*)d_in[0];
    const float* T = (const float*)d_in[1];
    float* ws  = (float*)d_ws;
    float* out = (float*)d_out;

    init_kernel<<<1, 1, 0, stream>>>(ws);
    rkd_mfma_kernel<<<512, 256, 0, stream>>>(S, T, ws, out);
}

// Round 3
// 78.694 us; speedup vs baseline: 1.4455x; 1.0686x over previous
//
#include <hip/hip_runtime.h>

typedef short short8 __attribute__((ext_vector_type(8)));
typedef float f32x4 __attribute__((ext_vector_type(4)));
typedef unsigned short ushort;

#define DD 512

// ws layout:
//   bytes [0, 1MB)   : bf16 S' (1024 x 512)
//   bytes [1MB, 2MB) : bf16 T' (1024 x 512)
//   then float sqarr[4096]: [0..1023]=sq_s [1024..2047]=sq_t [2048..3071]=rn_s [3072..4095]=rn_t
//   then float acc; unsigned counter

__device__ __forceinline__ short to_bf16(float f) {
    unsigned int u = __float_as_uint(f);
    u += 0x7FFFu + ((u >> 16) & 1u);   // RNE (finite normals)
    return (short)(u >> 16);
}

__device__ __forceinline__ short8 pack8(float4 a, float4 b) {
    short8 r;
    r[0] = to_bf16(a.x); r[1] = to_bf16(a.y); r[2] = to_bf16(a.z); r[3] = to_bf16(a.w);
    r[4] = to_bf16(b.x); r[5] = to_bf16(b.y); r[6] = to_bf16(b.z); r[7] = to_bf16(b.w);
    return r;
}

__device__ __forceinline__ float dot4(float4 v) {
    return v.x*v.x + v.y*v.y + v.z*v.z + v.w*v.w;
}

// one wave per row (rows 0..1023 = S, 1024..2047 = T)
__global__ __launch_bounds__(64) void convert_kernel(const float* __restrict__ S,
                                                     const float* __restrict__ T,
                                                     ushort* __restrict__ bf,
                                                     float* __restrict__ sqarr,
                                                     float* __restrict__ accw) {
    const int idx  = blockIdx.x;
    const int lane = threadIdx.x;
    const float* src = (idx < 1024) ? (S + (size_t)idx * DD)
                                    : (T + (size_t)(idx - 1024) * DD);
    float4 v0 = ((const float4*)src)[lane * 2];
    float4 v1 = ((const float4*)src)[lane * 2 + 1];
    *(short8*)(bf + (size_t)idx * DD + lane * 8) = pack8(v0, v1);
    float s = dot4(v0) + dot4(v1);
    #pragma unroll
    for (int off = 32; off > 0; off >>= 1) s += __shfl_down(s, off);
    if (lane == 0) {
        sqarr[idx]        = s;                                  // fp32-exact sq
        sqarr[2048 + idx] = 1.0f / fmaxf(sqrtf(s), 1e-12f);     // reciprocal norm
        if (idx == 0) { accw[0] = 0.0f; ((unsigned int*)accw)[1] = 0u; }
    }
}

__global__ __launch_bounds__(256, 2) void rkd_tile_kernel(const ushort* __restrict__ bf,
                                                          const float* __restrict__ sqarr,
                                                          float* __restrict__ accw,
                                                          float* __restrict__ out) {
    // unpadded bf16 tiles (required by global_load_lds lane-contiguous dest).
    // Bank conflicts on fragment reads avoided by XOR chunk swizzle at staging.
    __shared__ ushort AS[64][64], AT[64][64];
    __shared__ ushort BS[32][64], BT[32][64];
    __shared__ float wsum[4];

    const int t = threadIdx.x;
    const int I = (blockIdx.x >> 5) * 64;   // 16 I-tiles
    const int J = (blockIdx.x & 31) * 32;   // 32 J-tiles
    const int w = t >> 6;
    const int L = t & 63;
    const int m = L & 15;
    const int quad = L >> 4;
    const int arow = w * 16 + m;

    const ushort* bS = bf;
    const ushort* bT = bf + (size_t)1024 * DD;

    // staging: wave-load q covers 8 rows x 64 k; lane L -> row L>>3, swizzled chunk
    const int lrow = L >> 3;                 // 0..7
    const int lchk = (L & 7) ^ lrow;         // XOR swizzle (rbase is multiple of 8)
    const int lgoff = lrow * DD + lchk * 8;  // bf16 units

    const ushort* gtab[6];
    ushort* ltab[6];
    #pragma unroll
    for (int j = 0; j < 6; ++j) {
        const int q = w * 6 + j;             // 0..23, wave-uniform
        const ushort* gmat; ushort* lmat; int rbase, gbase;
        if (q < 8)       { gmat = bS; lmat = &AS[0][0]; rbase = q * 8;        gbase = I; }
        else if (q < 16) { gmat = bT; lmat = &AT[0][0]; rbase = (q - 8) * 8;  gbase = I; }
        else if (q < 20) { gmat = bS; lmat = &BS[0][0]; rbase = (q - 16) * 8; gbase = J; }
        else             { gmat = bT; lmat = &BT[0][0]; rbase = (q - 20) * 8; gbase = J; }
        gtab[j] = gmat + (size_t)(gbase + rbase) * DD + lgoff;
        ltab[j] = lmat + rbase * 64;
    }

    f32x4 aS0 = {0,0,0,0}, aS1 = {0,0,0,0};
    f32x4 aT0 = {0,0,0,0}, aT1 = {0,0,0,0};

    for (int k0 = 0; k0 < DD; k0 += 64) {
        __syncthreads();   // previous iteration's fragment reads done
        #pragma unroll
        for (int j = 0; j < 6; ++j)
            __builtin_amdgcn_global_load_lds(
                (const __attribute__((address_space(1))) void*)(gtab[j] + k0),
                (__attribute__((address_space(3))) void*)ltab[j], 16, 0, 0);
        __syncthreads();   // barrier semantics drain vmcnt -> staging visible

        #pragma unroll
        for (int ks = 0; ks < 2; ++ks) {
            const int cs = (((ks * 4 + quad) ^ (m & 7))) * 8;  // de-swizzled slot
            short8 af_s = *(const short8*)&AS[arow][cs];
            short8 af_t = *(const short8*)&AT[arow][cs];
            short8 b_s0 = *(const short8*)&BS[m][cs];
            short8 b_s1 = *(const short8*)&BS[16 + m][cs];
            short8 b_t0 = *(const short8*)&BT[m][cs];
            short8 b_t1 = *(const short8*)&BT[16 + m][cs];
            aS0 = __builtin_amdgcn_mfma_f32_16x16x32_bf16(af_s, b_s0, aS0, 0, 0, 0);
            aS1 = __builtin_amdgcn_mfma_f32_16x16x32_bf16(af_s, b_s1, aS1, 0, 0, 0);
            aT0 = __builtin_amdgcn_mfma_f32_16x16x32_bf16(af_t, b_t0, aT0, 0, 0, 0);
            aT1 = __builtin_amdgcn_mfma_f32_16x16x32_bf16(af_t, b_t1, aT1, 0, 0, 0);
        }
    }

    // epilogue: C/D layout col = lane&15, row = quad*4 + reg (m89/m91)
    const int j0 = J + m, j1 = J + 16 + m;
    float js0 = sqarr[j0],        jt0 = sqarr[1024 + j0];
    float rjs0 = sqarr[2048 + j0], rjt0 = sqarr[3072 + j0];
    float js1 = sqarr[j1],        jt1 = sqarr[1024 + j1];
    float rjs1 = sqarr[2048 + j1], rjt1 = sqarr[3072 + j1];

    float local = 0.0f;
    const int ib = I + w * 16 + quad * 4;
    #pragma unroll
    for (int reg = 0; reg < 4; ++reg) {
        const int r = ib + reg;
        float is = sqarr[r],        it = sqarr[1024 + r];
        float ris = sqarr[2048 + r], rit = sqarr[3072 + r];

        float gs0 = aS0[reg], gt0 = aT0[reg];
        float d1 = gs0 * ris * rjs0 - gt0 * rit * rjt0;
        float d2 = (is + js0 - 2.0f * gs0) - (it + jt0 - 2.0f * gt0);
        local += d1 * d1 + d2 * d2;

        float gs1 = aS1[reg], gt1 = aT1[reg];
        float e1 = gs1 * ris * rjs1 - gt1 * rit * rjt1;
        float e2 = (is + js1 - 2.0f * gs1) - (it + jt1 - 2.0f * gt1);
        local += e1 * e1 + e2 * e2;
    }

    #pragma unroll
    for (int off = 32; off > 0; off >>= 1) local += __shfl_down(local, off);
    if (L == 0) wsum[w] = local;
    __syncthreads();

    if (t == 0) {
        float blk = wsum[0] + wsum[1] + wsum[2] + wsum[3];
        atomicAdd(&accw[0], blk);
        __threadfence();
        unsigned int old = atomicAdd((unsigned int*)accw + 1, 1u);
        if (old == 511u) {   // last of 512 blocks
            float tot = atomicAdd(&accw[0], 0.0f);
            out[0] = tot * (1.0f / 1048576.0f);
        }
    }
}

extern "C" void kernel_launch(void* const* d_in, const int* in_sizes, int n_in,
                              void* d_out, int out_size, void* d_ws, size_t ws_size,
                              hipStream_t stream) {
    const float* S = (const float*)d_in[0];
    const float* T = (const float*)d_in[1];
    ushort* bf   = (ushort*)d_ws;
    float* sqarr = (float*)((char*)d_ws + 2 * 1024 * 1024);
    float* accw  = sqarr + 4096;
    float* out   = (float*)d_out;

    convert_kernel<<<2048, 64, 0, stream>>>(S, T, bf, sqarr, accw);
    rkd_tile_kernel<<<512, 256, 0, stream>>>(bf, sqarr, accw, out);
}

// Round 4
// 75.934 us; speedup vs baseline: 1.4980x; 1.0363x over previous
//
#include <hip/hip_runtime.h>

typedef short short8 __attribute__((ext_vector_type(8)));
typedef float f32x4 __attribute__((ext_vector_type(4)));
typedef unsigned short ushort;

#define DD 512

// ws layout:
//   bytes [0, 1MB)   : bf16 S' (1024 x 512)
//   bytes [1MB, 2MB) : bf16 T' (1024 x 512)
//   float sqarr[4096]: [0..1023]=sq_s [1024..2047]=sq_t [2048..3071]=rn_s [3072..4095]=rn_t
//   float slots[16]; unsigned counter

__device__ __forceinline__ short to_bf16(float f) {
    unsigned int u = __float_as_uint(f);
    u += 0x7FFFu + ((u >> 16) & 1u);   // RNE (finite normals)
    return (short)(u >> 16);
}

__device__ __forceinline__ short8 pack8(float4 a, float4 b) {
    short8 r;
    r[0] = to_bf16(a.x); r[1] = to_bf16(a.y); r[2] = to_bf16(a.z); r[3] = to_bf16(a.w);
    r[4] = to_bf16(b.x); r[5] = to_bf16(b.y); r[6] = to_bf16(b.z); r[7] = to_bf16(b.w);
    return r;
}

__device__ __forceinline__ float dot4(float4 v) {
    return v.x*v.x + v.y*v.y + v.z*v.z + v.w*v.w;
}

// 512 blocks x 256: one wave per row (rows 0..1023 = S, 1024..2047 = T)
__global__ __launch_bounds__(256) void convert_kernel(const float* __restrict__ S,
                                                      const float* __restrict__ T,
                                                      ushort* __restrict__ bf,
                                                      float* __restrict__ sqarr,
                                                      float* __restrict__ accw) {
    const int t    = threadIdx.x;
    const int lane = t & 63;
    const int row  = blockIdx.x * 4 + (t >> 6);   // 0..2047
    const float* src = (row < 1024) ? (S + (size_t)row * DD)
                                    : (T + (size_t)(row - 1024) * DD);
    float4 v0 = ((const float4*)src)[lane * 2];
    float4 v1 = ((const float4*)src)[lane * 2 + 1];
    *(short8*)(bf + (size_t)row * DD + lane * 8) = pack8(v0, v1);
    float s = dot4(v0) + dot4(v1);
    #pragma unroll
    for (int off = 32; off > 0; off >>= 1) s += __shfl_down(s, off);
    if (lane == 0) {
        sqarr[row]        = s;                                // fp32-exact sq
        sqarr[2048 + row] = 1.0f / fmaxf(sqrtf(s), 1e-12f);   // reciprocal norm
    }
    if (blockIdx.x == 0 && t < 17) ((unsigned int*)(accw))[t] = 0u;  // 16 slots + counter
}

__global__ __launch_bounds__(256, 2) void rkd_tile_kernel(const ushort* __restrict__ bf,
                                                          const float* __restrict__ sqarr,
                                                          float* __restrict__ accw,
                                                          float* __restrict__ out) {
    // double-buffered unpadded bf16 tiles; per buffer (ushort units):
    //   AS @0 (64x64), AT @4096 (64x64), BS @8192 (32x64), BT @10240 (32x64) = 12288
    __shared__ ushort tiles[2][12288];
    __shared__ float wsum[4];

    const int t = threadIdx.x;
    const int I = (blockIdx.x >> 5) * 64;   // 16 I-tiles
    const int J = (blockIdx.x & 31) * 32;   // 32 J-tiles
    const int w = t >> 6;
    const int L = t & 63;
    const int m = L & 15;
    const int quad = L >> 4;
    const int arow = w * 16 + m;

    const ushort* bS = bf;
    const ushort* bT = bf + (size_t)1024 * DD;

    // staging: wave-load q covers 8 rows x 64 k; lane L -> row L>>3, XOR-swizzled chunk
    const int lrow  = L >> 3;                 // 0..7
    const int lchk  = (L & 7) ^ lrow;         // swizzle (rbase is a multiple of 8)
    const int lgoff = lrow * DD + lchk * 8;   // bf16 units, global side

    const ushort* gtab[6];
    int loff[6];
    #pragma unroll
    for (int j = 0; j < 6; ++j) {
        const int q = w * 6 + j;              // 0..23, wave-uniform
        const ushort* gmat; int gbase, lo;
        if (q < 8)       { gmat = bS; gbase = I; lo = 0     + q * 512; }
        else if (q < 16) { gmat = bT; gbase = I; lo = 4096  + (q - 8) * 512; }
        else if (q < 20) { gmat = bS; gbase = J; lo = 8192  + (q - 16) * 512; }
        else             { gmat = bT; gbase = J; lo = 10240 + (q - 20) * 512; }
        const int rbase = (lo & 4095) >> 6;   // not needed; row encoded in lo
        (void)rbase;
        gtab[j] = gmat + (size_t)gbase * DD + (size_t)((lo * 8) & 0) /*0*/ + lgoff
                  + (size_t)(((q < 8) ? q : (q < 16) ? (q - 8) : (q < 20) ? (q - 16) : (q - 20)) * 8) * DD;
        loff[j] = lo;
    }

    // hoist epilogue stats (L2/HBM latency overlapped with main loop)
    const int j0 = J + m, j1 = J + 16 + m;
    const float js0 = sqarr[j0],        jt0 = sqarr[1024 + j0];
    const float rjs0 = sqarr[2048 + j0], rjt0 = sqarr[3072 + j0];
    const float js1 = sqarr[j1],        jt1 = sqarr[1024 + j1];
    const float rjs1 = sqarr[2048 + j1], rjt1 = sqarr[3072 + j1];
    const int ib = I + w * 16 + quad * 4;
    float isv[4], itv[4], risv[4], ritv[4];
    #pragma unroll
    for (int reg = 0; reg < 4; ++reg) {
        isv[reg]  = sqarr[ib + reg];        itv[reg]  = sqarr[1024 + ib + reg];
        risv[reg] = sqarr[2048 + ib + reg]; ritv[reg] = sqarr[3072 + ib + reg];
    }

    f32x4 aS0 = {0,0,0,0}, aS1 = {0,0,0,0};
    f32x4 aT0 = {0,0,0,0}, aT1 = {0,0,0,0};

    // prefetch slab 0 into buffer 0
    #pragma unroll
    for (int j = 0; j < 6; ++j)
        __builtin_amdgcn_global_load_lds(
            (const __attribute__((address_space(1))) void*)(gtab[j]),
            (__attribute__((address_space(3))) void*)(&tiles[0][0] + loff[j]), 16, 0, 0);

    for (int i = 0; i < 8; ++i) {
        __syncthreads();   // drains vmcnt -> buf[i&1] staged; prior reads of other buf done
        if (i < 7) {
            const int nb = (i + 1) & 1;
            const int k0 = (i + 1) * 64;
            #pragma unroll
            for (int j = 0; j < 6; ++j)
                __builtin_amdgcn_global_load_lds(
                    (const __attribute__((address_space(1))) void*)(gtab[j] + k0),
                    (__attribute__((address_space(3))) void*)(&tiles[nb][0] + loff[j]), 16, 0, 0);
        }
        const ushort* base = &tiles[i & 1][0];
        #pragma unroll
        for (int ks = 0; ks < 2; ++ks) {
            const int cs = ((ks * 4 + quad) ^ (m & 7)) * 8;   // de-swizzled slot
            short8 af_s = *(const short8*)(base + arow * 64 + cs);
            short8 af_t = *(const short8*)(base + 4096 + arow * 64 + cs);
            short8 b_s0 = *(const short8*)(base + 8192 + m * 64 + cs);
            short8 b_s1 = *(const short8*)(base + 8192 + (16 + m) * 64 + cs);
            short8 b_t0 = *(const short8*)(base + 10240 + m * 64 + cs);
            short8 b_t1 = *(const short8*)(base + 10240 + (16 + m) * 64 + cs);
            aS0 = __builtin_amdgcn_mfma_f32_16x16x32_bf16(af_s, b_s0, aS0, 0, 0, 0);
            aS1 = __builtin_amdgcn_mfma_f32_16x16x32_bf16(af_s, b_s1, aS1, 0, 0, 0);
            aT0 = __builtin_amdgcn_mfma_f32_16x16x32_bf16(af_t, b_t0, aT0, 0, 0, 0);
            aT1 = __builtin_amdgcn_mfma_f32_16x16x32_bf16(af_t, b_t1, aT1, 0, 0, 0);
        }
    }

    // epilogue: C/D layout col = lane&15, row = quad*4 + reg (m89/m91)
    float local = 0.0f;
    #pragma unroll
    for (int reg = 0; reg < 4; ++reg) {
        float is = isv[reg], it = itv[reg], ris = risv[reg], rit = ritv[reg];

        float gs0 = aS0[reg], gt0 = aT0[reg];
        float d1 = gs0 * ris * rjs0 - gt0 * rit * rjt0;
        float d2 = (is + js0 - 2.0f * gs0) - (it + jt0 - 2.0f * gt0);
        local += d1 * d1 + d2 * d2;

        float gs1 = aS1[reg], gt1 = aT1[reg];
        float e1 = gs1 * ris * rjs1 - gt1 * rit * rjt1;
        float e2 = (is + js1 - 2.0f * gs1) - (it + jt1 - 2.0f * gt1);
        local += e1 * e1 + e2 * e2;
    }

    #pragma unroll
    for (int off = 32; off > 0; off >>= 1) local += __shfl_down(local, off);
    if (L == 0) wsum[w] = local;
    __syncthreads();

    if (t == 0) {
        float blk = wsum[0] + wsum[1] + wsum[2] + wsum[3];
        atomicAdd(&accw[blockIdx.x & 15], blk);   // 16-way spread: ~32 RMW per address
        __threadfence();
        unsigned int old = atomicAdd((unsigned int*)(accw + 16), 1u);
        if (old == 511u) {   // last of 512 blocks
            __threadfence();
            float tot = 0.0f;
            #pragma unroll
            for (int s2 = 0; s2 < 16; ++s2)
                tot += __hip_atomic_load(&accw[s2], __ATOMIC_RELAXED, __HIP_MEMORY_SCOPE_AGENT);
            out[0] = tot * (1.0f / 1048576.0f);
        }
    }
}

extern "C" void kernel_launch(void* const* d_in, const int* in_sizes, int n_in,
                              void* d_out, int out_size, void* d_ws, size_t ws_size,
                              hipStream_t stream) {
    const float* S = (const float*)d_in[0];
    const float* T = (const float*)d_in[1];
    ushort* bf   = (ushort*)d_ws;
    float* sqarr = (float*)((char*)d_ws + 2 * 1024 * 1024);
    float* accw  = sqarr + 4096;
    float* out   = (float*)d_out;

    convert_kernel<<<512, 256, 0, stream>>>(S, T, bf, sqarr, accw);
    rkd_tile_kernel<<<512, 256, 0, stream>>>(bf, sqarr, accw, out);
}

// Round 5
// 72.717 us; speedup vs baseline: 1.5643x; 1.0442x over previous
//
#include <hip/hip_runtime.h>

typedef short short8 __attribute__((ext_vector_type(8)));
typedef float f32x16 __attribute__((ext_vector_type(16)));
typedef unsigned short ushort;

#define DD 512

// ws layout:
//   bytes [0, 1MB)   : bf16 S' (1024 x 512)
//   bytes [1MB, 2MB) : bf16 T' (1024 x 512)
//   float sqarr[4096]: [0..1023]=sq_s [1024..2047]=sq_t [2048..3071]=rn_s [3072..4095]=rn_t
//   float slots[16]; unsigned counter

__device__ __forceinline__ short to_bf16(float f) {
    unsigned int u = __float_as_uint(f);
    u += 0x7FFFu + ((u >> 16) & 1u);   // RNE (finite normals)
    return (short)(u >> 16);
}

__device__ __forceinline__ short8 pack8(float4 a, float4 b) {
    short8 r;
    r[0] = to_bf16(a.x); r[1] = to_bf16(a.y); r[2] = to_bf16(a.z); r[3] = to_bf16(a.w);
    r[4] = to_bf16(b.x); r[5] = to_bf16(b.y); r[6] = to_bf16(b.z); r[7] = to_bf16(b.w);
    return r;
}

__device__ __forceinline__ float dot4(float4 v) {
    return v.x*v.x + v.y*v.y + v.z*v.z + v.w*v.w;
}

// 512 blocks x 256: one wave per row (rows 0..1023 = S, 1024..2047 = T)
__global__ __launch_bounds__(256) void convert_kernel(const float* __restrict__ S,
                                                      const float* __restrict__ T,
                                                      ushort* __restrict__ bf,
                                                      float* __restrict__ sqarr,
                                                      float* __restrict__ accw) {
    const int t    = threadIdx.x;
    const int lane = t & 63;
    const int row  = blockIdx.x * 4 + (t >> 6);   // 0..2047
    const float* src = (row < 1024) ? (S + (size_t)row * DD)
                                    : (T + (size_t)(row - 1024) * DD);
    float4 v0 = ((const float4*)src)[lane * 2];
    float4 v1 = ((const float4*)src)[lane * 2 + 1];
    *(short8*)(bf + (size_t)row * DD + lane * 8) = pack8(v0, v1);
    float s = dot4(v0) + dot4(v1);
    #pragma unroll
    for (int off = 32; off > 0; off >>= 1) s += __shfl_down(s, off);
    if (lane == 0) {
        sqarr[row]        = s;                                // fp32-exact sq
        sqarr[2048 + row] = 1.0f / fmaxf(sqrtf(s), 1e-12f);   // reciprocal norm
    }
    if (blockIdx.x == 0 && t < 17) ((unsigned int*)(accw))[t] = 0u;  // 16 slots + counter
}

__global__ __launch_bounds__(256) void rkd_tile_kernel(const ushort* __restrict__ bf,
                                                       const float* __restrict__ sqarr,
                                                       float* __restrict__ accw,
                                                       float* __restrict__ out) {
    // double-buffered unpadded bf16 tiles; per buffer (ushort units):
    //   AS @0 (64x64), AT @4096, BS @8192, BT @12288  -> 16384 ushorts = 32 KB
    __shared__ ushort tiles[2][16384];
    __shared__ float statI[4][64];   // [0]=sq_s [1]=sq_t [2]=rn_s [3]=rn_t for I-rows
    __shared__ float statJ[4][64];   // same for J-cols
    __shared__ float wsum[4];

    const int t = threadIdx.x;
    const int I = (blockIdx.x >> 4) * 64;   // 16 I-tiles
    const int J = (blockIdx.x & 15) * 64;   // 16 J-tiles
    const int w = t >> 6;
    const int L = t & 63;
    const int c = L & 31;   // col/row within 32-wide mfma tile
    const int h = L >> 5;   // k-half selector (8 bf16)
    const int rowsel = (w & 1) * 32;
    const int colsel = (w >> 1) * 32;

    const ushort* bS = bf;
    const ushort* bT = bf + (size_t)1024 * DD;

    // stage per-row stats into LDS (epilogue reads are then broadcast ds_reads)
    {
        const int a = t >> 6, r = t & 63;
        const int so = a * 1024;   // 0,1024,2048,3072
        statI[a][r] = sqarr[so + I + r];
        statJ[a][r] = sqarr[so + J + r];
    }

    // staging: wave-load q covers 8 rows x 64 k; lane L -> row L>>3, XOR-swizzled chunk
    const int lrow  = L >> 3;                 // 0..7
    const int lchk  = (L & 7) ^ lrow;         // swizzle (row base is a multiple of 8)
    const int lgoff = lrow * DD + lchk * 8;   // bf16 units, global side

    const ushort* gtab[8];
    int loff[8];
    #pragma unroll
    for (int j = 0; j < 8; ++j) {
        const int q   = w * 8 + j;        // 0..31, wave-uniform
        const int ts  = q >> 3;           // 0:AS 1:AT 2:BS 3:BT
        const int sub = q & 7;            // 8-row subtile within the 64-row tile
        const ushort* gmat = (ts == 0 || ts == 2) ? bS : bT;
        const int gbase = (ts < 2) ? I : J;
        gtab[j] = gmat + (size_t)(gbase + sub * 8) * DD + lgoff;
        loff[j] = ts * 4096 + sub * 512;
    }

    f32x16 accS, accT;
    #pragma unroll
    for (int i2 = 0; i2 < 16; ++i2) { accS[i2] = 0.0f; accT[i2] = 0.0f; }

    // prefetch slab 0 into buffer 0
    #pragma unroll
    for (int j = 0; j < 8; ++j)
        __builtin_amdgcn_global_load_lds(
            (const __attribute__((address_space(1))) void*)(gtab[j]),
            (__attribute__((address_space(3))) void*)(&tiles[0][0] + loff[j]), 16, 0, 0);

    for (int i = 0; i < 8; ++i) {
        __syncthreads();   // drains vmcnt -> buf[i&1] staged; prior reads of other buf done
        if (i < 7) {
            const int k0 = (i + 1) * 64;
            ushort* nb = &tiles[(i + 1) & 1][0];
            #pragma unroll
            for (int j = 0; j < 8; ++j)
                __builtin_amdgcn_global_load_lds(
                    (const __attribute__((address_space(1))) void*)(gtab[j] + k0),
                    (__attribute__((address_space(3))) void*)(nb + loff[j]), 16, 0, 0);
        }
        const ushort* base = &tiles[i & 1][0];
        #pragma unroll
        for (int step = 0; step < 4; ++step) {
            // wanted 8-bf16 unit = step*2 + h, stored at slot (unit ^ (row&7))
            const int us = ((step * 2 + h) ^ (c & 7)) * 8;
            short8 afS = *(const short8*)(base + (rowsel + c) * 64 + us);
            short8 afT = *(const short8*)(base + 4096 + (rowsel + c) * 64 + us);
            short8 bfS = *(const short8*)(base + 8192 + (colsel + c) * 64 + us);
            short8 bfT = *(const short8*)(base + 12288 + (colsel + c) * 64 + us);
            accS = __builtin_amdgcn_mfma_f32_32x32x16_bf16(afS, bfS, accS, 0, 0, 0);
            accT = __builtin_amdgcn_mfma_f32_32x32x16_bf16(afT, bfT, accT, 0, 0, 0);
        }
    }

    // epilogue: 32x32 C/D layout col = lane&31, row = (reg&3) + 8*(reg>>2) + 4*(lane>>5)
    const int colg = colsel + c;
    const float js  = statJ[0][colg], jt  = statJ[1][colg];
    const float rjs = statJ[2][colg], rjt = statJ[3][colg];

    float local = 0.0f;
    #pragma unroll
    for (int reg = 0; reg < 16; ++reg) {
        const int rowg = rowsel + (reg & 3) + 8 * (reg >> 2) + 4 * h;
        float is  = statI[0][rowg], it  = statI[1][rowg];
        float ris = statI[2][rowg], rit = statI[3][rowg];
        float gs = accS[reg], gt = accT[reg];
        float d1 = gs * ris * rjs - gt * rit * rjt;
        float d2 = (is + js - 2.0f * gs) - (it + jt - 2.0f * gt);
        local += d1 * d1 + d2 * d2;
    }

    #pragma unroll
    for (int off = 32; off > 0; off >>= 1) local += __shfl_down(local, off);
    if (L == 0) wsum[w] = local;
    __syncthreads();

    if (t == 0) {
        float blk = wsum[0] + wsum[1] + wsum[2] + wsum[3];
        atomicAdd(&accw[blockIdx.x & 15], blk);   // 16-way spread: 16 RMW per address
        __threadfence();
        unsigned int old = atomicAdd((unsigned int*)(accw + 16), 1u);
        if (old == 255u) {   // last of 256 blocks
            __threadfence();
            float tot = 0.0f;
            #pragma unroll
            for (int s2 = 0; s2 < 16; ++s2)
                tot += __hip_atomic_load(&accw[s2], __ATOMIC_RELAXED, __HIP_MEMORY_SCOPE_AGENT);
            out[0] = tot * (1.0f / 1048576.0f);
        }
    }
}

extern "C" void kernel_launch(void* const* d_in, const int* in_sizes, int n_in,
                              void* d_out, int out_size, void* d_ws, size_t ws_size,
                              hipStream_t stream) {
    const float* S = (const float*)d_in[0];
    const float* T = (const float*)d_in[1];
    ushort* bf   = (ushort*)d_ws;
    float* sqarr = (float*)((char*)d_ws + 2 * 1024 * 1024);
    float* accw  = sqarr + 4096;
    float* out   = (float*)d_out;

    convert_kernel<<<512, 256, 0, stream>>>(S, T, bf, sqarr, accw);
    rkd_tile_kernel<<<256, 256, 0, stream>>>(bf, sqarr, accw, out);
}

// Round 6
// 71.938 us; speedup vs baseline: 1.5812x; 1.0108x over previous
//
#include <hip/hip_runtime.h>

typedef short short8 __attribute__((ext_vector_type(8)));
typedef float f32x16 __attribute__((ext_vector_type(16)));
typedef unsigned short ushort;

#define DD 512

// ws layout:
//   bytes [0, 1MB)   : bf16 S' (1024 x 512)
//   bytes [1MB, 2MB) : bf16 T' (1024 x 512)
//   float sqarr[4096]: [0..1023]=sq_s [1024..2047]=sq_t [2048..3071]=rn_s [3072..4095]=rn_t
//   float slots[16]; unsigned counter

__device__ __forceinline__ short to_bf16(float f) {
    unsigned int u = __float_as_uint(f);
    u += 0x7FFFu + ((u >> 16) & 1u);   // RNE (finite normals)
    return (short)(u >> 16);
}

__device__ __forceinline__ short8 pack8(float4 a, float4 b) {
    short8 r;
    r[0] = to_bf16(a.x); r[1] = to_bf16(a.y); r[2] = to_bf16(a.z); r[3] = to_bf16(a.w);
    r[4] = to_bf16(b.x); r[5] = to_bf16(b.y); r[6] = to_bf16(b.z); r[7] = to_bf16(b.w);
    return r;
}

__device__ __forceinline__ float dot4(float4 v) {
    return v.x*v.x + v.y*v.y + v.z*v.z + v.w*v.w;
}

// 512 blocks x 256: one wave per row (rows 0..1023 = S, 1024..2047 = T)
__global__ __launch_bounds__(256) void convert_kernel(const float* __restrict__ S,
                                                      const float* __restrict__ T,
                                                      ushort* __restrict__ bf,
                                                      float* __restrict__ sqarr,
                                                      float* __restrict__ accw) {
    const int t    = threadIdx.x;
    const int lane = t & 63;
    const int row  = blockIdx.x * 4 + (t >> 6);   // 0..2047
    const float* src = (row < 1024) ? (S + (size_t)row * DD)
                                    : (T + (size_t)(row - 1024) * DD);
    float4 v0 = ((const float4*)src)[lane * 2];
    float4 v1 = ((const float4*)src)[lane * 2 + 1];
    *(short8*)(bf + (size_t)row * DD + lane * 8) = pack8(v0, v1);
    float s = dot4(v0) + dot4(v1);
    #pragma unroll
    for (int off = 32; off > 0; off >>= 1) s += __shfl_down(s, off);
    if (lane == 0) {
        sqarr[row]        = s;                                // fp32-exact sq
        sqarr[2048 + row] = 1.0f / fmaxf(sqrtf(s), 1e-12f);   // reciprocal norm
    }
    if (blockIdx.x == 0 && t < 17) ((unsigned int*)(accw))[t] = 0u;  // 16 slots + counter
}

// 272 blocks x 128 threads: upper-triangle 32x64 tiles, symmetric weighting.
// Block tile: rows I..I+31 (A), cols J..J+63 (B); wave w owns cols J+32w..+31.
__global__ __launch_bounds__(128) void rkd_tile_kernel(const ushort* __restrict__ bf,
                                                       const float* __restrict__ sqarr,
                                                       float* __restrict__ accw,
                                                       float* __restrict__ out) {
    // double-buffered bf16 tiles, per buffer (ushort units):
    //   AS @0 (32x64), AT @2048, BS @4096 (64x64), BT @8192 -> 12288 ushorts = 24 KB
    __shared__ ushort tiles[2][12288];
    __shared__ float statI[4][32];   // sq_s / sq_t / rn_s / rn_t for I-rows
    __shared__ float statJ[4][64];   // same for J-cols
    __shared__ float wsum[2];

    const int t = threadIdx.x;

    // decode upper-triangle tile: for I-tile a (32 rows), J-tiles b = a/2 .. 15
    int rem = blockIdx.x, a = 0;
    for (;;) { int cnt = 16 - (a >> 1); if (rem < cnt) break; rem -= cnt; ++a; }
    const int b2 = (a >> 1) + rem;
    const int I = a * 32;
    const int J = b2 * 64;

    const int w = t >> 6;       // 0..1
    const int L = t & 63;
    const int c = L & 31;
    const int h = L >> 5;
    const int colsel = w * 32;

    const ushort* bS = bf;
    const ushort* bT = bf + (size_t)1024 * DD;

    // stage per-row stats into LDS
    {
        const int a2 = t >> 5, r = t & 31;     // a2: 0..3
        statI[a2][r]      = sqarr[a2 * 1024 + I + r];
        statJ[a2][r]      = sqarr[a2 * 1024 + J + r];
        statJ[a2][32 + r] = sqarr[a2 * 1024 + J + 32 + r];
    }

    // staging: each wave issues 12 load_lds, each covering 8 rows x 64 k
    const int lrow  = L >> 3;
    const int lchk  = (L & 7) ^ lrow;          // XOR swizzle (subtile base multiple of 8)
    const int lgoff = lrow * DD + lchk * 8;

    const ushort* gtab[12];
    int loff[12];
    #pragma unroll
    for (int j = 0; j < 12; ++j) {
        const int q = w * 12 + j;              // 0..23, wave-uniform
        const ushort* gmat; int gbase, lo, sub;
        if (q < 4)       { gmat = bS; gbase = I; sub = q;      lo = 0    + sub * 512; }
        else if (q < 8)  { gmat = bT; gbase = I; sub = q - 4;  lo = 2048 + sub * 512; }
        else if (q < 16) { gmat = bS; gbase = J; sub = q - 8;  lo = 4096 + sub * 512; }
        else             { gmat = bT; gbase = J; sub = q - 16; lo = 8192 + sub * 512; }
        gtab[j] = gmat + (size_t)(gbase + sub * 8) * DD + lgoff;
        loff[j] = lo;
    }

    f32x16 accS, accT;
    #pragma unroll
    for (int i2 = 0; i2 < 16; ++i2) { accS[i2] = 0.0f; accT[i2] = 0.0f; }

    // prefetch slab 0
    #pragma unroll
    for (int j = 0; j < 12; ++j)
        __builtin_amdgcn_global_load_lds(
            (const __attribute__((address_space(1))) void*)(gtab[j]),
            (__attribute__((address_space(3))) void*)(&tiles[0][0] + loff[j]), 16, 0, 0);

    for (int i = 0; i < 8; ++i) {
        __syncthreads();   // drains vmcnt -> buf[i&1] staged; prior reads of other buf done
        if (i < 7) {
            const int k0 = (i + 1) * 64;
            ushort* nb = &tiles[(i + 1) & 1][0];
            #pragma unroll
            for (int j = 0; j < 12; ++j)
                __builtin_amdgcn_global_load_lds(
                    (const __attribute__((address_space(1))) void*)(gtab[j] + k0),
                    (__attribute__((address_space(3))) void*)(nb + loff[j]), 16, 0, 0);
        }
        const ushort* base = &tiles[i & 1][0];
        #pragma unroll
        for (int step = 0; step < 4; ++step) {
            const int us = ((step * 2 + h) ^ (c & 7)) * 8;   // de-swizzled slot
            short8 afS = *(const short8*)(base + c * 64 + us);
            short8 afT = *(const short8*)(base + 2048 + c * 64 + us);
            short8 bS8 = *(const short8*)(base + 4096 + (colsel + c) * 64 + us);
            short8 bT8 = *(const short8*)(base + 8192 + (colsel + c) * 64 + us);
            accS = __builtin_amdgcn_mfma_f32_32x32x16_bf16(afS, bS8, accS, 0, 0, 0);
            accT = __builtin_amdgcn_mfma_f32_32x32x16_bf16(afT, bT8, accT, 0, 0, 0);
        }
    }

    // epilogue: C/D col = lane&31, row = (reg&3) + 8*(reg>>2) + 4*(lane>>5) (m74/m101)
    const int colg = colsel + c;
    const int jg   = J + colg;
    const float js  = statJ[0][colg], jt  = statJ[1][colg];
    const float rjs = statJ[2][colg], rjt = statJ[3][colg];

    float local = 0.0f;
    #pragma unroll
    for (int reg = 0; reg < 16; ++reg) {
        const int rowg = (reg & 3) + 8 * (reg >> 2) + 4 * h;
        const int ig = I + rowg;
        float wgt = (jg > ig) ? 2.0f : ((jg == ig) ? 1.0f : 0.0f);  // symmetry weight
        float is  = statI[0][rowg], it  = statI[1][rowg];
        float ris = statI[2][rowg], rit = statI[3][rowg];
        float gs = accS[reg], gt = accT[reg];
        float d1 = gs * ris * rjs - gt * rit * rjt;
        float d2 = (is + js - 2.0f * gs) - (it + jt - 2.0f * gt);
        local += wgt * (d1 * d1 + d2 * d2);
    }

    #pragma unroll
    for (int off = 32; off > 0; off >>= 1) local += __shfl_down(local, off);
    if (L == 0) wsum[w] = local;
    __syncthreads();

    if (t == 0) {
        float blk = wsum[0] + wsum[1];
        atomicAdd(&accw[blockIdx.x & 15], blk);   // 16-way spread
        __threadfence();
        unsigned int old = atomicAdd((unsigned int*)(accw + 16), 1u);
        if (old == 271u) {   // last of 272 blocks
            __threadfence();
            float tot = 0.0f;
            #pragma unroll
            for (int s2 = 0; s2 < 16; ++s2)
                tot += __hip_atomic_load(&accw[s2], __ATOMIC_RELAXED, __HIP_MEMORY_SCOPE_AGENT);
            out[0] = tot * (1.0f / 1048576.0f);
        }
    }
}

extern "C" void kernel_launch(void* const* d_in, const int* in_sizes, int n_in,
                              void* d_out, int out_size, void* d_ws, size_t ws_size,
                              hipStream_t stream) {
    const float* S = (const float*)d_in[0];
    const float* T = (const float*)d_in[1];
    ushort* bf   = (ushort*)d_ws;
    float* sqarr = (float*)((char*)d_ws + 2 * 1024 * 1024);
    float* accw  = sqarr + 4096;
    float* out   = (float*)d_out;

    convert_kernel<<<512, 256, 0, stream>>>(S, T, bf, sqarr, accw);
    rkd_tile_kernel<<<272, 128, 0, stream>>>(bf, sqarr, accw, out);
}